// Round 4
// baseline (35.270 us; speedup 1.0000x reference)
//
#include <hip/hip_runtime.h>

#define NCELLS (4*4*128*128)    // 262144 cells
#define BLOCK  256
#define NBLK   2048             // 2 blocks per 256-cell chunk (half of samples each)
#define S_HALF 8                // samples per half; 16 total per cell

// murmur3 finalizer — bijective, strong avalanche; counter-based RNG
__device__ __forceinline__ unsigned fmix32(unsigned h) {
    h ^= h >> 16;
    h *= 0x85ebca6bu;
    h ^= h >> 13;
    h *= 0xc2b2ae35u;
    h ^= h >> 16;
    return h;
}

__global__ __launch_bounds__(BLOCK) void crps_mc_kernel(
    const float* __restrict__ alpha,
    const float* __restrict__ beta,
    const float* __restrict__ weights,
    const float* __restrict__ y_true,
    float* __restrict__ partial)
{
    const int chunk = blockIdx.x >> 1;          // which 256-cell chunk
    const int half  = blockIdx.x & 1;           // which sample half
    const int cell  = chunk * BLOCK + threadIdx.x;

    // M=4 innermost -> one float4 per cell, fully coalesced
    const float4 a4 = reinterpret_cast<const float4*>(alpha)[cell];
    const float4 b4 = reinterpret_cast<const float4*>(beta)[cell];
    const float y   = y_true[cell];

    // integer-quantized mixture CDF (8-bit); components exchangeable across
    // cells so quantization bias cancels (~1e-6)
    const float w0 = weights[0], w1 = weights[1], w2 = weights[2];
    const unsigned k0 = (unsigned)(w0 * 256.0f + 0.5f);
    const unsigned k1 = (unsigned)((w0 + w1) * 256.0f + 0.5f);
    const unsigned k2 = (unsigned)((w0 + w1 + w2) * 256.0f + 0.5f);

    const float ia0 = __builtin_amdgcn_rcpf(a4.x), ia1 = __builtin_amdgcn_rcpf(a4.y);
    const float ia2 = __builtin_amdgcn_rcpf(a4.z), ia3 = __builtin_amdgcn_rcpf(a4.w);
    const float ib0 = __builtin_amdgcn_rcpf(b4.x), ib1 = __builtin_amdgcn_rcpf(b4.y);
    const float ib2 = __builtin_amdgcn_rcpf(b4.z), ib3 = __builtin_amdgcn_rcpf(b4.w);

    const unsigned base = (unsigned)cell * 32u + (unsigned)half * (unsigned)S_HALF;

    // one Kumaraswamy mixture draw from one 32-bit hash (inlined; independent
    // calls have no cross-dependencies -> scheduler interleaves the chains)
    auto draw = [&](unsigned n) -> float {
        const unsigned h = fmix32(n);
        const unsigned cb = h & 0xFFu;            // component (low 8 bits)
        float ia = ia0, ib = ib0;
        if (cb >= k0) { ia = ia1; ib = ib1; }
        if (cb >= k1) { ia = ia2; ib = ib2; }
        if (cb >= k2) { ia = ia3; ib = ib3; }
        // v = 1-u bit trick: f = 1.[23 bits] in [1,2), v = 2 - f in (0,1]
        const float f = __int_as_float(0x3f800000u | (h >> 9));
        const float v = 2.0f - f;
        const float p = __builtin_amdgcn_exp2f(ib * __builtin_amdgcn_logf(v));
        const float w = fmaxf(1.0f - p, 0.0f);    // guard approx error -> NaN
        return __builtin_amdgcn_exp2f(ia * __builtin_amdgcn_logf(w)); // w==0 -> 0
    };

    float t1 = 0.0f;   // sum |x - y| over 8 samples
    float t2 = 0.0f;   // sum |x - x'| over 4 disjoint pairs (unbiased E|X-X'|)

    // 2 iterations x 4 independent chains (ILP=4)
    #pragma unroll
    for (int s = 0; s < S_HALF; s += 4) {
        const float xA = draw(base + (unsigned)s);
        const float xB = draw(base + (unsigned)s + 1u);
        const float xC = draw(base + (unsigned)s + 2u);
        const float xD = draw(base + (unsigned)s + 3u);
        t1 += (fabsf(xA - y) + fabsf(xB - y)) + (fabsf(xC - y) + fabsf(xD - y));
        t2 += fabsf(xA - xB) + fabsf(xC - xD);
    }

    // per-half contribution: 8/16 of term1 samples, 4/8 of term2 pairs
    float val = t1 * (1.0f / 16.0f) - t2 * (0.5f / 8.0f);

    // wave64 shuffle reduce
    #pragma unroll
    for (int off = 32; off > 0; off >>= 1)
        val += __shfl_down(val, off, 64);

    __shared__ float red[BLOCK / 64];
    if ((threadIdx.x & 63) == 0) red[threadIdx.x >> 6] = val;
    __syncthreads();
    if (threadIdx.x == 0) {
        float s = 0.0f;
        #pragma unroll
        for (int i = 0; i < BLOCK / 64; ++i) s += red[i];
        partial[blockIdx.x] = s;
    }
}

__global__ __launch_bounds__(BLOCK) void crps_reduce_kernel(
    const float* __restrict__ partial, float* __restrict__ out)
{
    const int t = threadIdx.x;
    float v = 0.0f;
    #pragma unroll
    for (int k = 0; k < NBLK / BLOCK; ++k)
        v += partial[t + k * BLOCK];
    #pragma unroll
    for (int off = 32; off > 0; off >>= 1)
        v += __shfl_down(v, off, 64);
    __shared__ float red[BLOCK / 64];
    if ((t & 63) == 0) red[t >> 6] = v;
    __syncthreads();
    if (t == 0) {
        float s = 0.0f;
        #pragma unroll
        for (int i = 0; i < BLOCK / 64; ++i) s += red[i];
        out[0] = s * (1.0f / NCELLS);
    }
}

extern "C" void kernel_launch(void* const* d_in, const int* in_sizes, int n_in,
                              void* d_out, int out_size, void* d_ws, size_t ws_size,
                              hipStream_t stream) {
    // setup_inputs order: alpha, beta, weights, y_true, i_idx, j_idx
    const float* alpha   = (const float*)d_in[0];
    const float* beta    = (const float*)d_in[1];
    const float* weights = (const float*)d_in[2];
    const float* y_true  = (const float*)d_in[3];
    // i_idx / j_idx unused: disjoint in-thread pairs give the same expectation

    float* partial = (float*)d_ws;  // 2048 floats = 8 KB scratch

    crps_mc_kernel<<<NBLK, BLOCK, 0, stream>>>(alpha, beta, weights, y_true, partial);
    crps_reduce_kernel<<<1, BLOCK, 0, stream>>>(partial, (float*)d_out);
}

// Round 5
// 11.898 us; speedup vs baseline: 2.9644x; 2.9644x over previous
//
#include <hip/hip_runtime.h>

#define NCELLS (4*4*128*128)    // 262144 cells
#define BLOCK  256
#define NBLK   2048             // 2 blocks per 256-cell chunk (half of samples each)
#define S_HALF 8                // samples per half; 16 total per cell

// murmur3 finalizer — bijective, strong avalanche; counter-based RNG
__device__ __forceinline__ unsigned fmix32(unsigned h) {
    h ^= h >> 16;
    h *= 0x85ebca6bu;
    h ^= h >> 13;
    h *= 0xc2b2ae35u;
    h ^= h >> 16;
    return h;
}

__global__ __launch_bounds__(BLOCK) void crps_mc_kernel(
    const float* __restrict__ alpha,
    const float* __restrict__ beta,
    const float* __restrict__ weights,
    const float* __restrict__ y_true,
    float* __restrict__ partial)
{
    const int chunk = blockIdx.x >> 1;          // which 256-cell chunk
    const int half  = blockIdx.x & 1;           // which sample half
    const int cell  = chunk * BLOCK + threadIdx.x;

    // M=4 innermost -> one float4 per cell, fully coalesced
    const float4 a4 = reinterpret_cast<const float4*>(alpha)[cell];
    const float4 b4 = reinterpret_cast<const float4*>(beta)[cell];
    const float y   = y_true[cell];

    // integer-quantized mixture CDF (8-bit); components exchangeable across
    // cells so quantization bias cancels (~1e-6)
    const float w0 = weights[0], w1 = weights[1], w2 = weights[2];
    const unsigned k0 = (unsigned)(w0 * 256.0f + 0.5f);
    const unsigned k1 = (unsigned)((w0 + w1) * 256.0f + 0.5f);
    const unsigned k2 = (unsigned)((w0 + w1 + w2) * 256.0f + 0.5f);

    const float ia0 = __builtin_amdgcn_rcpf(a4.x), ia1 = __builtin_amdgcn_rcpf(a4.y);
    const float ia2 = __builtin_amdgcn_rcpf(a4.z), ia3 = __builtin_amdgcn_rcpf(a4.w);
    const float ib0 = __builtin_amdgcn_rcpf(b4.x), ib1 = __builtin_amdgcn_rcpf(b4.y);
    const float ib2 = __builtin_amdgcn_rcpf(b4.z), ib3 = __builtin_amdgcn_rcpf(b4.w);

    const unsigned base = (unsigned)cell * 32u + (unsigned)half * (unsigned)S_HALF;

    float t1 = 0.0f;   // sum |x - y| over 8 samples
    float t2 = 0.0f;   // sum |x - x'| over 4 disjoint pairs (unbiased E|X-X'|)

    // 2 iterations x 4 chains, MANUALLY stage-interleaved: round 2<->3<->4 A/B/A
    // proved the scheduler serializes per-sample chains unless the source
    // overlaps their live ranges stage by stage (VGPR 28 = serialized, slow).
    #pragma unroll
    for (int s = 0; s < S_HALF; s += 4) {
        // stage 0: hashes (independent integer chains)
        const unsigned hA = fmix32(base + (unsigned)s);
        const unsigned hB = fmix32(base + (unsigned)s + 1u);
        const unsigned hC = fmix32(base + (unsigned)s + 2u);
        const unsigned hD = fmix32(base + (unsigned)s + 3u);

        // stage 1: component select (integer CDF compare on low 8 bits)
        const unsigned cA = hA & 0xFFu, cB = hB & 0xFFu, cC = hC & 0xFFu, cD = hD & 0xFFu;
        float iaA = ia0, ibA = ib0;
        if (cA >= k0) { iaA = ia1; ibA = ib1; }
        if (cA >= k1) { iaA = ia2; ibA = ib2; }
        if (cA >= k2) { iaA = ia3; ibA = ib3; }
        float iaB = ia0, ibB = ib0;
        if (cB >= k0) { iaB = ia1; ibB = ib1; }
        if (cB >= k1) { iaB = ia2; ibB = ib2; }
        if (cB >= k2) { iaB = ia3; ibB = ib3; }
        float iaC = ia0, ibC = ib0;
        if (cC >= k0) { iaC = ia1; ibC = ib1; }
        if (cC >= k1) { iaC = ia2; ibC = ib2; }
        if (cC >= k2) { iaC = ia3; ibC = ib3; }
        float iaD = ia0, ibD = ib0;
        if (cD >= k0) { iaD = ia1; ibD = ib1; }
        if (cD >= k1) { iaD = ia2; ibD = ib2; }
        if (cD >= k2) { iaD = ia3; ibD = ib3; }

        // stage 2: v = 1-u bit trick: f = 1.[23 bits] in [1,2), v = 2-f in (0,1]
        const float vA = 2.0f - __int_as_float(0x3f800000u | (hA >> 9));
        const float vB = 2.0f - __int_as_float(0x3f800000u | (hB >> 9));
        const float vC = 2.0f - __int_as_float(0x3f800000u | (hC >> 9));
        const float vD = 2.0f - __int_as_float(0x3f800000u | (hD >> 9));

        // stage 3: first log (4 independent trans ops back to back)
        const float lA = __builtin_amdgcn_logf(vA);
        const float lB = __builtin_amdgcn_logf(vB);
        const float lC = __builtin_amdgcn_logf(vC);
        const float lD = __builtin_amdgcn_logf(vD);

        // stage 4: first exp2
        const float pA = __builtin_amdgcn_exp2f(ibA * lA);
        const float pB = __builtin_amdgcn_exp2f(ibB * lB);
        const float pC = __builtin_amdgcn_exp2f(ibC * lC);
        const float pD = __builtin_amdgcn_exp2f(ibD * lD);

        // stage 5: w = max(1-p, 0) (guard approx error -> NaN)
        const float wA = fmaxf(1.0f - pA, 0.0f);
        const float wB = fmaxf(1.0f - pB, 0.0f);
        const float wC = fmaxf(1.0f - pC, 0.0f);
        const float wD = fmaxf(1.0f - pD, 0.0f);

        // stage 6: second log
        const float mA = __builtin_amdgcn_logf(wA);
        const float mB = __builtin_amdgcn_logf(wB);
        const float mC = __builtin_amdgcn_logf(wC);
        const float mD = __builtin_amdgcn_logf(wD);

        // stage 7: second exp2 (w==0 -> exp2(-inf)=0, ok)
        const float xA = __builtin_amdgcn_exp2f(iaA * mA);
        const float xB = __builtin_amdgcn_exp2f(iaB * mB);
        const float xC = __builtin_amdgcn_exp2f(iaC * mC);
        const float xD = __builtin_amdgcn_exp2f(iaD * mD);

        // accumulate
        t1 += (fabsf(xA - y) + fabsf(xB - y)) + (fabsf(xC - y) + fabsf(xD - y));
        t2 += fabsf(xA - xB) + fabsf(xC - xD);
    }

    // per-half contribution: 8/16 of term1 samples, 4/8 of term2 pairs
    float val = t1 * (1.0f / 16.0f) - t2 * (0.5f / 8.0f);

    // wave64 shuffle reduce
    #pragma unroll
    for (int off = 32; off > 0; off >>= 1)
        val += __shfl_down(val, off, 64);

    __shared__ float red[BLOCK / 64];
    if ((threadIdx.x & 63) == 0) red[threadIdx.x >> 6] = val;
    __syncthreads();
    if (threadIdx.x == 0) {
        float s = 0.0f;
        #pragma unroll
        for (int i = 0; i < BLOCK / 64; ++i) s += red[i];
        partial[blockIdx.x] = s;
    }
}

__global__ __launch_bounds__(BLOCK) void crps_reduce_kernel(
    const float* __restrict__ partial, float* __restrict__ out)
{
    const int t = threadIdx.x;
    float v = 0.0f;
    #pragma unroll
    for (int k = 0; k < NBLK / BLOCK; ++k)
        v += partial[t + k * BLOCK];
    #pragma unroll
    for (int off = 32; off > 0; off >>= 1)
        v += __shfl_down(v, off, 64);
    __shared__ float red[BLOCK / 64];
    if ((t & 63) == 0) red[t >> 6] = v;
    __syncthreads();
    if (t == 0) {
        float s = 0.0f;
        #pragma unroll
        for (int i = 0; i < BLOCK / 64; ++i) s += red[i];
        out[0] = s * (1.0f / NCELLS);
    }
}

extern "C" void kernel_launch(void* const* d_in, const int* in_sizes, int n_in,
                              void* d_out, int out_size, void* d_ws, size_t ws_size,
                              hipStream_t stream) {
    // setup_inputs order: alpha, beta, weights, y_true, i_idx, j_idx
    const float* alpha   = (const float*)d_in[0];
    const float* beta    = (const float*)d_in[1];
    const float* weights = (const float*)d_in[2];
    const float* y_true  = (const float*)d_in[3];
    // i_idx / j_idx unused: disjoint in-thread pairs give the same expectation

    float* partial = (float*)d_ws;  // 2048 floats = 8 KB scratch

    crps_mc_kernel<<<NBLK, BLOCK, 0, stream>>>(alpha, beta, weights, y_true, partial);
    crps_reduce_kernel<<<1, BLOCK, 0, stream>>>(partial, (float*)d_out);
}